// Round 18
// baseline (111.885 us; speedup 1.0000x reference)
//
#include <hip/hip_runtime.h>
#include <math.h>

// SCARF KNN+LBS-blend kernel.  B=1, N=32768, V=10475, K=6, J=55.
// out = [ xyz_dist (N floats) | xyz_transform (N*16 floats) ]
//
// NUMERICS (verified rounds 3-7,9-11,13,16,17): x4-SCALED domain, coords
// doubled (exact). LDS stores s = (4x, 4y, 4z, t2'), t2' = 4*t2_ref exact.
// Screening: d' = fma(-Pz,sz, fma(-Py,sy, fma(-Px,sx, t2'))) — fma neg
// modifiers are free and sign-exact, bit-identical to r17's (-4x) layout.
// |d' + q' - d_exact| <= eps ~ 1.5e-4 (scaled); GMARG = 1e-3 >> 2*eps.
// Exact reference d recomputed per survivor at rebuild from global tpl:
// X = t+t, t2' = (X*X+Y*Y)+Z*Z, C' = fma(Pz,Z, fma(Py,Y, Px*X)),
// d = fmaf(-2, C', q'+t2') — bit-equal to np reference x4. Unscale 0.25f.
// Contraction off globally.
//
// ROUND 18 — wave-uniform pass-2 gate (branch-machinery kill):
//  * r13 vs r17 isolate per-tile costs: pass-1 ~0.95us/tile, pass-2
//    ~4.5us/tile — the 4 divergent per-point ifs/iter (saveexec+cbranch+
//    restore, ~always skipped) dominate pass 2.
//  * Fused predicate pre = min4(dp_r - G_r); `if (__any(pre<=0))` compiles
//    to a scalar vccz branch (no exec masking) skipping the push block
//    ~75% of iterations; per-point masked pushes only inside.
//  * Staging stores +4x (negation moved into free fma input modifiers).
//  * Everything else byte-identical to r17 (passed, 104us).
#pragma clang fp contract(off)

#define NPTS  32768
#define NV    10475
#define JW    55
#define TILE  512
#define NT    21          // 21*512 = 10752 >= NV (tail sentinel-padded)
#define NINIT 10          // pass-1 prefix tiles (5120 verts)
#define BLOCK 256
#define R     4           // points per wave
#define PPB   16          // 4 waves * 4 points -> grid 2048 (8 blocks/CU)
#define CAP   60          // survivor indices per point (E ~12.3, P(ovf)~4e-10)
#define FINF  3.4e38f
#define GMARG 0.001f      // >> 2*eps (eps ~ 1.5e-4, scaled domain)

#define FOR4(M) M(0) M(1) M(2) M(3)

// lexicographic (dist, idx) insert (jax top_k tie rule: lower idx wins on ties)
#define LTL(dd, vv, D, I) ((dd) < (D) || ((dd) == (D) && (vv) < (I)))
#define INSL6(dd, vv, D0,I0,D1,I1,D2,I2,D3,I3,D4,I4,D5,I5) \
  if (LTL(dd, vv, D5, I5)) { \
    if (LTL(dd, vv, D4, I4)) { D5=D4; I5=I4; \
      if (LTL(dd, vv, D3, I3)) { D4=D3; I4=I3; \
        if (LTL(dd, vv, D2, I2)) { D3=D2; I3=I2; \
          if (LTL(dd, vv, D1, I1)) { D2=D1; I2=I1; \
            if (LTL(dd, vv, D0, I0)) { D1=D0; I1=I0; D0=(dd); I0=(vv); } \
            else { D1=(dd); I1=(vv); } \
          } else { D2=(dd); I2=(vv); } \
        } else { D3=(dd); I3=(vv); } \
      } else { D4=(dd); I4=(vv); } \
    } else { D5=(dd); I5=(vv); } \
  }

__global__ __launch_bounds__(BLOCK, 8)
void scarf_knn_lbs(const float* __restrict__ lbs,   // [NV][JW]
                   const float* __restrict__ vtf,   // [NV][16]
                   const float* __restrict__ pts,   // [NPTS][3]
                   const float* __restrict__ tpl,   // [NV][3]
                   float* __restrict__ out_dist,    // [NPTS]
                   float* __restrict__ out_tf)      // [NPTS][16]
{
    __shared__ float4 s_tile[2][TILE];     // 16,384 B ping-pong
    __shared__ int    s_bi[PPB][CAP + 1];  //  3,904 B (slot [CAP] = counter)
                                           //  total 20,288 B -> 8 blocks/CU

    const int tid = threadIdx.x;
    const int h   = tid & 63;            // lane in wave
    const int w   = tid >> 6;            // wave 0..3
    const int lp  = w * R;               // wave's base local point
    const int p0  = blockIdx.x * PPB + lp;

    if (tid < PPB) s_bi[tid][CAP] = 0;

    // ---- 4 query points per wave, doubled coords (exact), q' = 4*p2_ref ----
    #define DECLP(r) \
      const float Px##r = 2.0f * pts[(p0+(r))*3+0]; \
      const float Py##r = 2.0f * pts[(p0+(r))*3+1]; \
      const float Pz##r = 2.0f * pts[(p0+(r))*3+2]; \
      const float q##r  = (Px##r*Px##r + Py##r*Py##r) + Pz##r*Pz##r;
    FOR4(DECLP)

    // staging: thread loads verts j = t*TILE + k*BLOCK + tid, k=0,1
    float gx[2], gy[2], gz[2];
    #define STAGE_ISSUE(t_) { \
      _Pragma("unroll") \
      for (int k = 0; k < 2; ++k) { \
        const int j = (t_) * TILE + k * BLOCK + tid; \
        if (j < NV) { gx[k] = tpl[j*3+0]; gy[k] = tpl[j*3+1]; gz[k] = tpl[j*3+2]; } \
        else        { gx[k] = 1.0e6f;    gy[k] = 1.0e6f;    gz[k] = 1.0e6f;    } } }
    // store (+4x, +4y, +4z, t2'); slot k*BLOCK+tid: conflict-free b128 writes
    #define STAGE_WRITE(dst_) { \
      _Pragma("unroll") \
      for (int k = 0; k < 2; ++k) { \
        const float X = gx[k]+gx[k], Y = gy[k]+gy[k], Z = gz[k]+gz[k]; \
        s_tile[dst_][k * BLOCK + tid] = \
          make_float4(X+X, Y+Y, Z+Z, (X*X + Y*Y) + Z*Z); } }

    // ================= pass 1: per-lane min of d' over the PREFIX ==========
    #define DECLM(r) float m##r = FINF;
    FOR4(DECLM)

    // d' = t2' - 4p.t via free fma negation modifiers (sign-exact)
    #define EVP1(r) { \
      const float da = fmaf(-Pz##r, ta.z, fmaf(-Py##r, ta.y, fmaf(-Px##r, ta.x, ta.w))); \
      const float db = fmaf(-Pz##r, tb.z, fmaf(-Py##r, tb.y, fmaf(-Px##r, tb.x, tb.w))); \
      m##r = fminf(fminf(m##r, da), db); }

    STAGE_ISSUE(0); STAGE_WRITE(0); __syncthreads();
    for (int t = 0; t < NINIT; ++t) {
        if (t + 1 < NINIT) STAGE_ISSUE(t + 1);
        const float4* bp = s_tile[t & 1];
        #pragma unroll
        for (int itp = 0; itp < 4; ++itp) {
            const float4 ta = bp[(2*itp    ) * 64 + h];
            const float4 tb = bp[(2*itp + 1) * 64 + h];
            FOR4(EVP1)
        }
        if (t + 1 < NINIT) { STAGE_WRITE((t + 1) & 1); __syncthreads(); }
    }

    // ---- gate: 6th smallest DISTINCT of 64 lane minima (prefix) + margin ----
    #define DECLT(r) float G##r; { \
      float v = m##r; float M; \
      _Pragma("unroll") \
      for (int rep = 0; rep < 6; ++rep) { \
        M = v; \
        M = fminf(M, __shfl_xor(M, 1)); \
        M = fminf(M, __shfl_xor(M, 2)); \
        M = fminf(M, __shfl_xor(M, 4)); \
        M = fminf(M, __shfl_xor(M, 8)); \
        M = fminf(M, __shfl_xor(M, 16)); \
        M = fminf(M, __shfl_xor(M, 32)); \
        if (rep < 5) v = (v == M) ? FINF : v; \
      } \
      G##r = M + GMARG; }
    FOR4(DECLT)

    __syncthreads();   // all waves done with prefix buffers before restage

    // ===== pass 2: full scan; wave-uniform __any gate; push INDEX only =====
    #define EVD(r) const float dp##r = \
      fmaf(-Pz##r, tv.z, fmaf(-Py##r, tv.y, fmaf(-Px##r, tv.x, tv.w)));
    #define PUSH(r) if (dp##r <= G##r) { \
        const int k = atomicAdd(&s_bi[lp+(r)][CAP], 1); \
        if (k < CAP) s_bi[lp+(r)][k] = tb + it*64 + h; }

    STAGE_ISSUE(0); STAGE_WRITE(0); __syncthreads();
    for (int t = 0; t < NT; ++t) {
        if (t + 1 < NT) STAGE_ISSUE(t + 1);
        const float4* bp = s_tile[t & 1];
        const int tb = t * TILE;
        #pragma unroll
        for (int it = 0; it < 8; ++it) {
            const float4 tv = bp[it * 64 + h];
            FOR4(EVD)
            const float pre = fminf(fminf(dp0 - G0, dp1 - G1),
                                    fminf(dp2 - G2, dp3 - G3));
            if (__any(pre <= 0.0f)) {   // scalar vccz branch, no exec masking
                FOR4(PUSH)
            }
        }
        if (t + 1 < NT) { STAGE_WRITE((t + 1) & 1); __syncthreads(); }
    }
    // survivor buffers are wave-private from here on (same-wave LDS ordering)

    // ---- exact top-6 per point: builder lanes h<4 recompute bit-exact d ----
    float D0=FINF,D1=FINF,D2=FINF,D3=FINF,D4=FINF,D5=FINF;
    int   I0=-1,I1=-1,I2=-1,I3=-1,I4=-1,I5=-1;
    if (h < R) {
        const int lpr = lp + h;
        const float Phx = (h==0)?Px0:(h==1)?Px1:(h==2)?Px2:Px3;
        const float Phy = (h==0)?Py0:(h==1)?Py1:(h==2)?Py2:Py3;
        const float Phz = (h==0)?Pz0:(h==1)?Pz1:(h==2)?Pz2:Pz3;
        const float qh  = (h==0)?q0 :(h==1)?q1 :(h==2)?q2 :q3;
        const int cc = s_bi[lpr][CAP];
        const int c  = (cc < CAP) ? cc : CAP;
        for (int k = 0; k < c; ++k) {
            const int vv = s_bi[lpr][k];
            const float tx = tpl[vv*3+0], ty = tpl[vv*3+1], tz = tpl[vv*3+2];
            const float X = tx+tx, Y = ty+ty, Z = tz+tz;   // identical bits to staged
            const float t2 = (X*X + Y*Y) + Z*Z;
            const float C  = fmaf(Phz, Z, fmaf(Phy, Y, Phx * X));
            const float de = fmaxf(fmaf(-2.0f, C, qh + t2), 0.0f); // bit-exact ref
            INSL6(de, vv, D0,I0,D1,I1,D2,I2,D3,I3,D4,I4,D5,I5);
        }
    }

    // ---- broadcast top-6 from builder lane r (same wave) ----
    const int r  = h >> 4;            // point 0..3
    const int l  = h & 15;            // sub-lane 0..15
    const int i0 = __shfl(I0, r), i1 = __shfl(I1, r), i2 = __shfl(I2, r);
    const int i3 = __shfl(I3, r), i4 = __shfl(I4, r), i5 = __shfl(I5, r);
    // unscale: 0.25f * (4*dd_ref) = dd_ref exactly
    const float d0 = 0.25f * __shfl(D0, r), d1 = 0.25f * __shfl(D1, r);
    const float d2 = 0.25f * __shfl(D2, r), d3 = 0.25f * __shfl(D3, r);
    const float d4 = 0.25f * __shfl(D4, r), d5 = 0.25f * __shfl(D5, r);

    // ---- confidence: 16 lanes cooperate per point (coalesced + tree reduce) ----
    {
        float s1 = 0.0f, s2 = 0.0f, s3 = 0.0f, s4 = 0.0f, s5 = 0.0f;
        for (int j = l; j < JW; j += 16) {
            const float w0 = lbs[(long)i0 * JW + j];
            s1 += fabsf(lbs[(long)i1 * JW + j] - w0);
            s2 += fabsf(lbs[(long)i2 * JW + j] - w0);
            s3 += fabsf(lbs[(long)i3 * JW + j] - w0);
            s4 += fabsf(lbs[(long)i4 * JW + j] - w0);
            s5 += fabsf(lbs[(long)i5 * JW + j] - w0);
        }
        s1 += __shfl_xor(s1,1); s1 += __shfl_xor(s1,2); s1 += __shfl_xor(s1,4); s1 += __shfl_xor(s1,8);
        s2 += __shfl_xor(s2,1); s2 += __shfl_xor(s2,2); s2 += __shfl_xor(s2,4); s2 += __shfl_xor(s2,8);
        s3 += __shfl_xor(s3,1); s3 += __shfl_xor(s3,2); s3 += __shfl_xor(s3,4); s3 += __shfl_xor(s3,8);
        s4 += __shfl_xor(s4,1); s4 += __shfl_xor(s4,2); s4 += __shfl_xor(s4,4); s4 += __shfl_xor(s4,8);
        s5 += __shfl_xor(s5,1); s5 += __shfl_xor(s5,2); s5 += __shfl_xor(s5,4); s5 += __shfl_xor(s5,8);
        const float sv = (l==0)?s1:(l==1)?s2:(l==2)?s3:(l==3)?s4:s5;
        const bool pred = (l < 5) && (expf(-sv / 0.02f) > 0.9f);
        const unsigned long long bal = __ballot(pred);
        const unsigned mr = (unsigned)(bal >> (r * 16)) & 31u;

        // ---- outputs: lane (point r, elem l) -> coalesced 64B rows ----
        const int P = p0 + r;
        const float w0 = expf(-d0);
        const float w1 = (mr & 1u)  ? expf(-d1) : 0.0f;
        const float w2 = (mr & 2u)  ? expf(-d2) : 0.0f;
        const float w3 = (mr & 4u)  ? expf(-d3) : 0.0f;
        const float w4 = (mr & 8u)  ? expf(-d4) : 0.0f;
        const float w5 = (mr & 16u) ? expf(-d5) : 0.0f;
        const float inv = 1.0f / (w0 + w1 + w2 + w3 + w4 + w5);
        const float n0 = w0*inv, n1 = w1*inv, n2 = w2*inv;
        const float n3 = w3*inv, n4 = w4*inv, n5 = w5*inv;

        if (l == 0)
            out_dist[P] = n0*d0 + n1*d1 + n2*d2 + n3*d3 + n4*d4 + n5*d5;

        float acc = n0 * vtf[i0*16 + l];
        acc = fmaf(n1, vtf[i1*16 + l], acc);
        acc = fmaf(n2, vtf[i2*16 + l], acc);
        acc = fmaf(n3, vtf[i3*16 + l], acc);
        acc = fmaf(n4, vtf[i4*16 + l], acc);
        acc = fmaf(n5, vtf[i5*16 + l], acc);
        out_tf[P*16 + l] = acc;
    }
}

extern "C" void kernel_launch(void* const* d_in, const int* in_sizes, int n_in,
                              void* d_out, int out_size, void* d_ws, size_t ws_size,
                              hipStream_t stream) {
    const float* lbs = (const float*)d_in[0];   // [10475][55]
    const float* vtf = (const float*)d_in[1];   // [10475][4][4]
    const float* pts = (const float*)d_in[2];   // [32768][3]
    const float* tpl = (const float*)d_in[3];   // [10475][3]
    float* out = (float*)d_out;
    scarf_knn_lbs<<<NPTS / PPB, BLOCK, 0, stream>>>(lbs, vtf, pts, tpl, out, out + NPTS);
}

// Round 19
// 103.374 us; speedup vs baseline: 1.0823x; 1.0823x over previous
//
#include <hip/hip_runtime.h>
#include <math.h>

// SCARF KNN+LBS-blend kernel.  B=1, N=32768, V=10475, K=6, J=55.
// out = [ xyz_dist (N floats) | xyz_transform (N*16 floats) ]
//
// NUMERICS (verified rounds 3-7,9-11,13,16,17): x4-SCALED domain, coords
// doubled (exact). LDS stores s = (-4x, -4y, -4z, t2'), t2' = 4*t2_ref
// exact. Screening: d' = fma(Pz,sz, fma(Py,sy, fma(Px,sx, t2'))) (3-fma),
// |d' + q' - d_exact| <= eps ~ 1.5e-4 (scaled); GMARG = 1e-3 >> 2*eps.
// Exact reference d recomputed per survivor at rebuild from global tpl:
// X = t+t, t2' = (X*X+Y*Y)+Z*Z, C' = fma(Pz,Z, fma(Py,Y, Px*X)),
// d = fmaf(-2, C', q'+t2') — bit-equal to np reference x4. Unscale 0.25f.
// Contraction off globally.
//
// ROUND 19 — r17 (best, 104.3us) + two overhead cuts; r18's __any gate
// REGRESSED (+7%: masked pushes were already cheap on the scalar pipe;
// the fused predicate added pure VALU) and is reverted.
//  * Staging guard only where needed: tiles 0..19 are full (max j=10239
//    < NV) -> unguarded loads; only tile 20 guarded. Pass 1 touches tiles
//    0..9 only -> fully unguarded.
//  * Pass-2 tile rotation (t+8)%21: tiles 8,9 are STILL RESIDENT in the
//    ping-pong buffers when pass 1 ends (staged at pass-1 t=7,t=8) ->
//    scan them first, no prologue staging; 19 stagings instead of 21.
//    Survivor rebuild is scan-order-independent (lexicographic total
//    order on (d,idx)) so rotation cannot change results.
#pragma clang fp contract(off)

#define NPTS  32768
#define NV    10475
#define JW    55
#define TILE  512
#define NT    21          // 21*512 = 10752 >= NV (tail sentinel-padded)
#define NINIT 10          // pass-1 prefix tiles (5120 verts)
#define BLOCK 256
#define R     4           // points per wave
#define PPB   16          // 4 waves * 4 points -> grid 2048 (8 blocks/CU)
#define CAP   60          // survivor indices per point (E ~12.3, P(ovf)~4e-10)
#define FINF  3.4e38f
#define GMARG 0.001f      // >> 2*eps (eps ~ 1.5e-4, scaled domain)

#define FOR4(M) M(0) M(1) M(2) M(3)

// lexicographic (dist, idx) insert (jax top_k tie rule: lower idx wins on ties)
#define LTL(dd, vv, D, I) ((dd) < (D) || ((dd) == (D) && (vv) < (I)))
#define INSL6(dd, vv, D0,I0,D1,I1,D2,I2,D3,I3,D4,I4,D5,I5) \
  if (LTL(dd, vv, D5, I5)) { \
    if (LTL(dd, vv, D4, I4)) { D5=D4; I5=I4; \
      if (LTL(dd, vv, D3, I3)) { D4=D3; I4=I3; \
        if (LTL(dd, vv, D2, I2)) { D3=D2; I3=I2; \
          if (LTL(dd, vv, D1, I1)) { D2=D1; I2=I1; \
            if (LTL(dd, vv, D0, I0)) { D1=D0; I1=I0; D0=(dd); I0=(vv); } \
            else { D1=(dd); I1=(vv); } \
          } else { D2=(dd); I2=(vv); } \
        } else { D3=(dd); I3=(vv); } \
      } else { D4=(dd); I4=(vv); } \
    } else { D5=(dd); I5=(vv); } \
  }

__global__ __launch_bounds__(BLOCK, 8)
void scarf_knn_lbs(const float* __restrict__ lbs,   // [NV][JW]
                   const float* __restrict__ vtf,   // [NV][16]
                   const float* __restrict__ pts,   // [NPTS][3]
                   const float* __restrict__ tpl,   // [NV][3]
                   float* __restrict__ out_dist,    // [NPTS]
                   float* __restrict__ out_tf)      // [NPTS][16]
{
    __shared__ float4 s_tile[2][TILE];     // 16,384 B ping-pong
    __shared__ int    s_bi[PPB][CAP + 1];  //  3,904 B (slot [CAP] = counter)
                                           //  total 20,288 B -> 8 blocks/CU

    const int tid = threadIdx.x;
    const int h   = tid & 63;            // lane in wave
    const int w   = tid >> 6;            // wave 0..3
    const int lp  = w * R;               // wave's base local point
    const int p0  = blockIdx.x * PPB + lp;

    if (tid < PPB) s_bi[tid][CAP] = 0;

    // ---- 4 query points per wave, doubled coords (exact), q' = 4*p2_ref ----
    #define DECLP(r) \
      const float Px##r = 2.0f * pts[(p0+(r))*3+0]; \
      const float Py##r = 2.0f * pts[(p0+(r))*3+1]; \
      const float Pz##r = 2.0f * pts[(p0+(r))*3+2]; \
      const float q##r  = (Px##r*Px##r + Py##r*Py##r) + Pz##r*Pz##r;
    FOR4(DECLP)

    // staging: thread loads verts j = t*TILE + k*BLOCK + tid, k=0,1
    float gx[2], gy[2], gz[2];
    // unguarded: for full tiles (tile*512 + 1023 < NV, i.e. tile <= 18;
    // tile 19 max j = 10239 < 10475 too -> tiles 0..19 safe)
    #define STAGE_ISSUE_F(t_) { \
      _Pragma("unroll") \
      for (int k = 0; k < 2; ++k) { \
        const int j = (t_) * TILE + k * BLOCK + tid; \
        gx[k] = tpl[j*3+0]; gy[k] = tpl[j*3+1]; gz[k] = tpl[j*3+2]; } }
    // guarded: only for tile 20 (sentinel tail)
    #define STAGE_ISSUE_G(t_) { \
      _Pragma("unroll") \
      for (int k = 0; k < 2; ++k) { \
        const int j = (t_) * TILE + k * BLOCK + tid; \
        if (j < NV) { gx[k] = tpl[j*3+0]; gy[k] = tpl[j*3+1]; gz[k] = tpl[j*3+2]; } \
        else        { gx[k] = 1.0e6f;    gy[k] = 1.0e6f;    gz[k] = 1.0e6f;    } } }
    // store (-4x, -4y, -4z, t2'); slot k*BLOCK+tid: conflict-free b128 writes
    #define STAGE_WRITE(dst_) { \
      _Pragma("unroll") \
      for (int k = 0; k < 2; ++k) { \
        const float X = gx[k]+gx[k], Y = gy[k]+gy[k], Z = gz[k]+gz[k]; \
        s_tile[dst_][k * BLOCK + tid] = \
          make_float4(-(X+X), -(Y+Y), -(Z+Z), (X*X + Y*Y) + Z*Z); } }

    // ================= pass 1: per-lane min of d' over the PREFIX ==========
    #define DECLM(r) float m##r = FINF;
    FOR4(DECLM)

    #define EVP1(r) { \
      const float da = fmaf(Pz##r, ta.z, fmaf(Py##r, ta.y, fmaf(Px##r, ta.x, ta.w))); \
      const float db = fmaf(Pz##r, tb.z, fmaf(Py##r, tb.y, fmaf(Px##r, tb.x, tb.w))); \
      m##r = fminf(fminf(m##r, da), db); }

    STAGE_ISSUE_F(0); STAGE_WRITE(0); __syncthreads();
    for (int t = 0; t < NINIT; ++t) {
        if (t + 1 < NINIT) STAGE_ISSUE_F(t + 1);
        const float4* bp = s_tile[t & 1];
        #pragma unroll
        for (int itp = 0; itp < 4; ++itp) {
            const float4 ta = bp[(2*itp    ) * 64 + h];
            const float4 tb = bp[(2*itp + 1) * 64 + h];
            FOR4(EVP1)
        }
        if (t + 1 < NINIT) { STAGE_WRITE((t + 1) & 1); __syncthreads(); }
    }
    // pass-1 leaves tile 8 in slot0, tile 9 in slot1 (staged at t=7, t=8)

    // ---- gate: 6th smallest DISTINCT of 64 lane minima (prefix) + margin ----
    #define DECLT(r) float G##r; { \
      float v = m##r; float M; \
      _Pragma("unroll") \
      for (int rep = 0; rep < 6; ++rep) { \
        M = v; \
        M = fminf(M, __shfl_xor(M, 1)); \
        M = fminf(M, __shfl_xor(M, 2)); \
        M = fminf(M, __shfl_xor(M, 4)); \
        M = fminf(M, __shfl_xor(M, 8)); \
        M = fminf(M, __shfl_xor(M, 16)); \
        M = fminf(M, __shfl_xor(M, 32)); \
        if (rep < 5) v = (v == M) ? FINF : v; \
      } \
      G##r = M + GMARG; }
    FOR4(DECLT)

    __syncthreads();   // all waves done with pass-1 reads of slots 0/1

    // ===== pass 2: rotated full scan (start at resident tiles 8,9);
    //       gate on d', push INDEX only =====
    #define EVP2(r) { \
      const float dp = fmaf(Pz##r, tv.z, fmaf(Py##r, tv.y, fmaf(Px##r, tv.x, tv.w))); \
      if (dp <= G##r) { \
        const int k = atomicAdd(&s_bi[lp+(r)][CAP], 1); \
        if (k < CAP) s_bi[lp+(r)][k] = tb + it*64 + h; } }

    for (int t = 0; t < NT; ++t) {
        const int tile = (t + 8 >= NT) ? (t + 8 - NT) : (t + 8);
        const int tn   = t + 1;
        if (tn < NT && tn >= 2) {
            const int tilenext = (tn + 8 >= NT) ? (tn + 8 - NT) : (tn + 8);
            if (tilenext == NT - 1) { STAGE_ISSUE_G(tilenext) }
            else                    { STAGE_ISSUE_F(tilenext) }
        }
        const float4* bp = s_tile[t & 1];
        const int tb = tile * TILE;
        #pragma unroll
        for (int it = 0; it < 8; ++it) {
            const float4 tv = bp[it * 64 + h];
            FOR4(EVP2)
        }
        if (tn < NT) {
            if (tn >= 2) STAGE_WRITE(tn & 1);
            __syncthreads();
        }
    }
    // survivor buffers are wave-private from here on (same-wave LDS ordering)

    // ---- exact top-6 per point: builder lanes h<4 recompute bit-exact d ----
    float D0=FINF,D1=FINF,D2=FINF,D3=FINF,D4=FINF,D5=FINF;
    int   I0=-1,I1=-1,I2=-1,I3=-1,I4=-1,I5=-1;
    if (h < R) {
        const int lpr = lp + h;
        const float Phx = (h==0)?Px0:(h==1)?Px1:(h==2)?Px2:Px3;
        const float Phy = (h==0)?Py0:(h==1)?Py1:(h==2)?Py2:Py3;
        const float Phz = (h==0)?Pz0:(h==1)?Pz1:(h==2)?Pz2:Pz3;
        const float qh  = (h==0)?q0 :(h==1)?q1 :(h==2)?q2 :q3;
        const int cc = s_bi[lpr][CAP];
        const int c  = (cc < CAP) ? cc : CAP;
        for (int k = 0; k < c; ++k) {
            const int vv = s_bi[lpr][k];
            const float tx = tpl[vv*3+0], ty = tpl[vv*3+1], tz = tpl[vv*3+2];
            const float X = tx+tx, Y = ty+ty, Z = tz+tz;   // identical bits to staged
            const float t2 = (X*X + Y*Y) + Z*Z;
            const float C  = fmaf(Phz, Z, fmaf(Phy, Y, Phx * X));
            const float de = fmaxf(fmaf(-2.0f, C, qh + t2), 0.0f); // bit-exact ref
            INSL6(de, vv, D0,I0,D1,I1,D2,I2,D3,I3,D4,I4,D5,I5);
        }
    }

    // ---- broadcast top-6 from builder lane r (same wave) ----
    const int r  = h >> 4;            // point 0..3
    const int l  = h & 15;            // sub-lane 0..15
    const int i0 = __shfl(I0, r), i1 = __shfl(I1, r), i2 = __shfl(I2, r);
    const int i3 = __shfl(I3, r), i4 = __shfl(I4, r), i5 = __shfl(I5, r);
    // unscale: 0.25f * (4*dd_ref) = dd_ref exactly
    const float d0 = 0.25f * __shfl(D0, r), d1 = 0.25f * __shfl(D1, r);
    const float d2 = 0.25f * __shfl(D2, r), d3 = 0.25f * __shfl(D3, r);
    const float d4 = 0.25f * __shfl(D4, r), d5 = 0.25f * __shfl(D5, r);

    // ---- confidence: 16 lanes cooperate per point (coalesced + tree reduce) ----
    {
        float s1 = 0.0f, s2 = 0.0f, s3 = 0.0f, s4 = 0.0f, s5 = 0.0f;
        for (int j = l; j < JW; j += 16) {
            const float w0 = lbs[(long)i0 * JW + j];
            s1 += fabsf(lbs[(long)i1 * JW + j] - w0);
            s2 += fabsf(lbs[(long)i2 * JW + j] - w0);
            s3 += fabsf(lbs[(long)i3 * JW + j] - w0);
            s4 += fabsf(lbs[(long)i4 * JW + j] - w0);
            s5 += fabsf(lbs[(long)i5 * JW + j] - w0);
        }
        s1 += __shfl_xor(s1,1); s1 += __shfl_xor(s1,2); s1 += __shfl_xor(s1,4); s1 += __shfl_xor(s1,8);
        s2 += __shfl_xor(s2,1); s2 += __shfl_xor(s2,2); s2 += __shfl_xor(s2,4); s2 += __shfl_xor(s2,8);
        s3 += __shfl_xor(s3,1); s3 += __shfl_xor(s3,2); s3 += __shfl_xor(s3,4); s3 += __shfl_xor(s3,8);
        s4 += __shfl_xor(s4,1); s4 += __shfl_xor(s4,2); s4 += __shfl_xor(s4,4); s4 += __shfl_xor(s4,8);
        s5 += __shfl_xor(s5,1); s5 += __shfl_xor(s5,2); s5 += __shfl_xor(s5,4); s5 += __shfl_xor(s5,8);
        const float sv = (l==0)?s1:(l==1)?s2:(l==2)?s3:(l==3)?s4:s5;
        const bool pred = (l < 5) && (expf(-sv / 0.02f) > 0.9f);
        const unsigned long long bal = __ballot(pred);
        const unsigned mr = (unsigned)(bal >> (r * 16)) & 31u;

        // ---- outputs: lane (point r, elem l) -> coalesced 64B rows ----
        const int P = p0 + r;
        const float w0 = expf(-d0);
        const float w1 = (mr & 1u)  ? expf(-d1) : 0.0f;
        const float w2 = (mr & 2u)  ? expf(-d2) : 0.0f;
        const float w3 = (mr & 4u)  ? expf(-d3) : 0.0f;
        const float w4 = (mr & 8u)  ? expf(-d4) : 0.0f;
        const float w5 = (mr & 16u) ? expf(-d5) : 0.0f;
        const float inv = 1.0f / (w0 + w1 + w2 + w3 + w4 + w5);
        const float n0 = w0*inv, n1 = w1*inv, n2 = w2*inv;
        const float n3 = w3*inv, n4 = w4*inv, n5 = w5*inv;

        if (l == 0)
            out_dist[P] = n0*d0 + n1*d1 + n2*d2 + n3*d3 + n4*d4 + n5*d5;

        float acc = n0 * vtf[i0*16 + l];
        acc = fmaf(n1, vtf[i1*16 + l], acc);
        acc = fmaf(n2, vtf[i2*16 + l], acc);
        acc = fmaf(n3, vtf[i3*16 + l], acc);
        acc = fmaf(n4, vtf[i4*16 + l], acc);
        acc = fmaf(n5, vtf[i5*16 + l], acc);
        out_tf[P*16 + l] = acc;
    }
}

extern "C" void kernel_launch(void* const* d_in, const int* in_sizes, int n_in,
                              void* d_out, int out_size, void* d_ws, size_t ws_size,
                              hipStream_t stream) {
    const float* lbs = (const float*)d_in[0];   // [10475][55]
    const float* vtf = (const float*)d_in[1];   // [10475][4][4]
    const float* pts = (const float*)d_in[2];   // [32768][3]
    const float* tpl = (const float*)d_in[3];   // [10475][3]
    float* out = (float*)d_out;
    scarf_knn_lbs<<<NPTS / PPB, BLOCK, 0, stream>>>(lbs, vtf, pts, tpl, out, out + NPTS);
}